// Round 6
// baseline (190.631 us; speedup 1.0000x reference)
//
#include <hip/hip_runtime.h>

#define NB 8
#define NC 256
#define NL 2048
#define SCALE 0.0625f   // C^-0.5 = 1/16

typedef __attribute__((ext_vector_type(8))) __bf16 bf16x8;
typedef __attribute__((ext_vector_type(4))) float f32x4;
typedef __attribute__((ext_vector_type(4))) unsigned int u32x4;
typedef __attribute__((ext_vector_type(2))) unsigned int u32x2;
typedef __attribute__((ext_vector_type(4))) unsigned short u16x4;
typedef __attribute__((ext_vector_type(8))) unsigned short u16x8;

// round-to-nearest-even fp32 -> bf16 bits
static __device__ __forceinline__ unsigned short f2b(float f) {
    unsigned int u = __builtin_bit_cast(unsigned int, f);
    u += 0x7fffu + ((u >> 16) & 1u);
    return (unsigned short)(u >> 16);
}

// ---------------------------------------------------------------------------
// Prep A: Wq/Wk/Wv fp32 -> bf16, concatenated [3][256][256].
// ---------------------------------------------------------------------------
__global__ void wconv_kernel(const float* __restrict__ Wq,
                             const float* __restrict__ Wk,
                             const float* __restrict__ Wv,
                             unsigned short* __restrict__ Wbf)
{
    const int base = (blockIdx.x * 256 + threadIdx.x) * 4;
    const int mat  = base >> 16;
    const int off  = base & 65535;
    const float* W = (mat == 0) ? Wq : (mat == 1) ? Wk : Wv;
    float4 w = *(const float4*)&W[off];
    u16x4 p = {f2b(w.x), f2b(w.y), f2b(w.z), f2b(w.w)};
    *(u16x4*)&Wbf[base] = p;
}

// ---------------------------------------------------------------------------
// Prep B: x [B][C][L] fp32 -> xT [B][L][C] bf16 (transpose via LDS).
// ---------------------------------------------------------------------------
__global__ __launch_bounds__(256, 2) void xprep_kernel(
    const float* __restrict__ x, unsigned short* __restrict__ xT)
{
    const int b  = blockIdx.z;
    const int c0 = blockIdx.y * 64;
    const int l0 = blockIdx.x * 64;
    const int t  = threadIdx.x;

    __shared__ unsigned short Tr[64][68];

    #pragma unroll
    for (int p = 0; p < 4; ++p) {
        const int c  = p * 16 + (t >> 4);
        const int lg = t & 15;
        float4 xv = *(const float4*)&x[((size_t)(b * NC + c0 + c)) * NL + l0 + lg * 4];
        u16x4 pk = {f2b(xv.x), f2b(xv.y), f2b(xv.z), f2b(xv.w)};
        *(u16x4*)&Tr[c][lg * 4] = pk;
    }
    __syncthreads();
    #pragma unroll
    for (int j = 0; j < 2; ++j) {
        const int chunk = t + 256 * j;      // 0..511
        const int l  = chunk >> 3;
        const int ck = chunk & 7;
        u16x8 o;
        #pragma unroll
        for (int i = 0; i < 8; ++i) o[i] = Tr[ck * 8 + i][l];
        *(u16x8*)&xT[((size_t)(b * NL + l0 + l)) * NC + c0 + ck * 8] = o;
    }
}

// ---------------------------------------------------------------------------
// Kernel 1: QKV projection via MFMA (verbatim from verified state).
// ---------------------------------------------------------------------------
__global__ __launch_bounds__(256, 2) void qkv_mfma(
    const unsigned short* __restrict__ xT,
    const unsigned short* __restrict__ Wbf,
    const float* __restrict__ bq, const float* __restrict__ bk,
    const float* __restrict__ bv,
    unsigned short* __restrict__ qT, unsigned short* __restrict__ kT,
    unsigned short* __restrict__ vo)
{
    const int raw = blockIdx.x;
    const int b   = raw & 7;          // XCD-pinned batch
    const int rem = raw >> 3;         // 0..95
    const int mat = rem >> 5;         // 0..2
    const int lt0 = (rem & 31) * 64;
    const int t    = threadIdx.x;
    const int w    = t >> 6;
    const int lane = t & 63;
    const int ln15 = lane & 15;
    const int quad = lane >> 4;

    __shared__ __align__(16) unsigned short XT[64 * 256];  // [l][c] swz, 32 KB
    __shared__ __align__(16) unsigned short WC[256 * 64];  // [o][c-chunk] swz, 32 KB

    const unsigned short* Wm = Wbf + mat * 65536;
    const float* bias = (mat == 0) ? bq : (mat == 1) ? bk : bv;

    float bvals[4][4];
    #pragma unroll
    for (int ot = 0; ot < 4; ++ot)
        #pragma unroll
        for (int r = 0; r < 4; ++r)
            bvals[ot][r] = bias[w * 64 + ot * 16 + quad * 4 + r];

    #pragma unroll
    for (int s = 0; s < 8; ++s) {
        const int il = w * 8 + s;
        const int n  = il * 2 + (lane >> 5);
        const int p  = lane & 31;
        const int g  = p ^ (n & 15);
        const unsigned short* gp = &xT[((size_t)(b * NL + lt0 + n)) * NC + g * 8];
        __builtin_amdgcn_global_load_lds(
            (const __attribute__((address_space(1))) unsigned int*)gp,
            (__attribute__((address_space(3))) unsigned int*)&XT[il * 512],
            16, 0, 0);
    }

    f32x4 acc[4][4];
    #pragma unroll
    for (int i = 0; i < 4; ++i)
        #pragma unroll
        for (int j = 0; j < 4; ++j) acc[i][j] = f32x4{0.f, 0.f, 0.f, 0.f};

    for (int k0 = 0; k0 < 4; ++k0) {
        if (k0) __syncthreads();
        #pragma unroll
        for (int s = 0; s < 8; ++s) {
            const int il = w * 8 + s;
            const int o  = il * 8 + (lane >> 3);
            const int p  = lane & 7;
            const int g  = p ^ (o & 7);
            const unsigned short* gp = &Wm[(size_t)o * NC + k0 * 64 + g * 8];
            __builtin_amdgcn_global_load_lds(
                (const __attribute__((address_space(1))) unsigned int*)gp,
                (__attribute__((address_space(3))) unsigned int*)&WC[il * 512],
                16, 0, 0);
        }
        __syncthreads();

        #pragma unroll
        for (int ks = 0; ks < 2; ++ks) {
            bf16x8 xf[4];
            #pragma unroll
            for (int lt = 0; lt < 4; ++lt) {
                const int l  = lt * 16 + ln15;
                const int kc = k0 * 8 + ks * 4 + quad;
                const int pp = kc ^ (l & 15);
                xf[lt] = __builtin_bit_cast(bf16x8, *(const u32x4*)&XT[l * 256 + pp * 8]);
            }
            #pragma unroll
            for (int ot = 0; ot < 4; ++ot) {
                const int o  = w * 64 + ot * 16 + ln15;
                const int pp = (ks * 4 + quad) ^ (o & 7);
                bf16x8 wf = __builtin_bit_cast(bf16x8, *(const u32x4*)&WC[o * 64 + pp * 8]);
                #pragma unroll
                for (int lt = 0; lt < 4; ++lt)
                    acc[ot][lt] = __builtin_amdgcn_mfma_f32_16x16x32_bf16(
                                      wf, xf[lt], acc[ot][lt], 0, 0, 0);
            }
        }
    }

    if (mat < 2) {
        unsigned short* out = (mat == 0) ? qT : kT;
        #pragma unroll
        for (int ot = 0; ot < 4; ++ot) {
            const int o_base = w * 64 + ot * 16 + quad * 4;
            #pragma unroll
            for (int lt = 0; lt < 4; ++lt) {
                const int l = lt0 + lt * 16 + ln15;
                u16x4 pk;
                #pragma unroll
                for (int r = 0; r < 4; ++r)
                    pk[r] = f2b(acc[ot][lt][r] + bvals[ot][r]);
                *(u16x4*)&out[((size_t)(b * NL + l)) * NC + o_base] = pk;
            }
        }
    } else {
        #pragma unroll
        for (int ot = 0; ot < 4; ++ot)
            #pragma unroll
            for (int lt = 0; lt < 4; ++lt) {
                const int l = lt0 + lt * 16 + ln15;
                #pragma unroll
                for (int r = 0; r < 4; ++r) {
                    const int o = w * 64 + ot * 16 + quad * 4 + r;
                    vo[((size_t)(b * NC + o)) * NL + l] = f2b(acc[ot][lt][r] + bvals[ot][r]);
                }
            }
    }
}

// ---------------------------------------------------------------------------
// Kernel 2: MFMA flash attention + residual. grid 256, block 1024 = 16 waves,
// 4 waves/SIMD. WAVE-SPECIALIZED pipeline (P double-buffered, one barrier per
// region):
//   waves 0..7  = QK(r): (kg 0..3, qh 0..1). Each holds TWO resident Q-frag
//                 sets (32 q-rows) and reads 8 K-frags -> 16 MFMAs: K-frag
//                 traffic halved vs R5 (each K byte read by 2 waves, not 4).
//                 exp + P-write (swizzle identical to R5) + in-register
//                 denominator partial via 2x shfl_xor (no ones-MFMAs).
//   waves 8..15 = PV(r-1): (qh 0..1, ch 0..3). Each computes 32q x 64c,
//                 K=64; every V-frag reused against 2 P-row frags -> V
//                 traffic halved. ctx[2][4], pa[2][2].
// LDS bytes/tile: 360 KB -> 232 KB (the measured bottleneck).
// K/V staging + swizzles byte-identical to R5 (verified).
// ---------------------------------------------------------------------------
__global__ __launch_bounds__(1024, 4) void attn_kernel(
    const unsigned short* __restrict__ qT,
    const unsigned short* __restrict__ kT,
    const unsigned short* __restrict__ v,
    const float* __restrict__ x,
    float* __restrict__ out)
{
    const int raw  = blockIdx.x;
    const int b    = raw & 7;         // XCD-pinned batch
    const int l0   = (raw >> 3) * 64;
    const int t    = threadIdx.x;
    const int w    = t >> 6;          // 0..15
    const int lane = t & 63;
    const int ln15 = lane & 15;
    const int quad = lane >> 4;
    const bool isQK = (w < 8);
    const int kg  = w & 3;            // QK waves: key group (16 keys)
    const int qh  = isQK ? (w >> 2) : ((w - 8) >> 2);  // q half (32 rows)
    const int ch  = (w - 8) & 3;      // PV waves: channel quarter (64 ch)

    __shared__ __align__(16) char smem[148480];
    unsigned short* Kb0 = (unsigned short*)smem;             // 32 KB
    unsigned short* Kb1 = (unsigned short*)(smem + 32768);   // 32 KB
    unsigned short* Vb0 = (unsigned short*)(smem + 65536);   // 32 KB
    unsigned short* Vb1 = (unsigned short*)(smem + 98304);   // 32 KB
    char* P0 = smem + 131072;                                //  8 KB [64q][64k] swz
    char* P1 = smem + 139264;                                //  8 KB
    float* denomLDS = (float*)(smem + 147456);               //  1 KB [4 kg][64 q]
    float (*buf)[68] = (float(*)[68])smem;                   // epilogue alias 69.6 KB

    // ---- QK waves: TWO resident Q fragment sets (rows qh*32 + 0..31) ----
    bf16x8 qf0[8], qf1[8];
    if (isQK) {
        const size_t qrow0 = ((size_t)b * NL + l0 + qh * 32 + ln15) * NC;
        const size_t qrow1 = qrow0 + (size_t)16 * NC;
        #pragma unroll
        for (int kt = 0; kt < 8; ++kt) {
            qf0[kt] = __builtin_bit_cast(bf16x8,
                         *(const u32x4*)&qT[qrow0 + kt * 32 + quad * 8]);
            qf1[kt] = __builtin_bit_cast(bf16x8,
                         *(const u32x4*)&qT[qrow1 + kt * 32 + quad * 8]);
        }
    }

    f32x4 ctx[2][4];
    #pragma unroll
    for (int i = 0; i < 2; ++i)
        #pragma unroll
        for (int j = 0; j < 4; ++j) ctx[i][j] = f32x4{0.f, 0.f, 0.f, 0.f};
    float dacc0 = 0.f, dacc1 = 0.f;

    auto stageK = [&](int mt, unsigned short* Kd) {
        const int m0 = mt * 64;
        #pragma unroll
        for (int s = 0; s < 2; ++s) {
            const int il = w * 2 + s;
            const int n  = il * 2 + (lane >> 5);
            const int g  = (lane & 31) ^ (n & 15);
            const unsigned short* gp = &kT[((size_t)b * NL + m0 + n) * NC + g * 8];
            __builtin_amdgcn_global_load_lds(
                (const __attribute__((address_space(1))) unsigned int*)gp,
                (__attribute__((address_space(3))) unsigned int*)&Kd[il * 512],
                16, 0, 0);
        }
    };
    auto stageV = [&](int mt, unsigned short* Vd) {
        const int m0 = mt * 64;
        #pragma unroll
        for (int s = 0; s < 2; ++s) {
            const int il = w * 2 + s;
            const int c  = il * 8 + (lane >> 3);
            const int g  = (lane & 7) ^ (c & 7);
            const unsigned short* gp = &v[((size_t)(b * NC + c)) * NL + m0 + g * 8];
            __builtin_amdgcn_global_load_lds(
                (const __attribute__((address_space(1))) unsigned int*)gp,
                (__attribute__((address_space(3))) unsigned int*)&Vd[il * 512],
                16, 0, 0);
        }
    };

    stageK(0, Kb0);
    __syncthreads();   // K(0) ready

    for (int r = 0; r <= 32; ++r) {
        // staging: K one tile ahead, V current (read by PV next region)
        if (r < 31) stageK(r + 1, ((r + 1) & 1) ? Kb1 : Kb0);
        if (r < 32) stageV(r, (r & 1) ? Vb1 : Vb0);

        if (isQK) {
            if (r < 32) {
                const unsigned short* Kd = (r & 1) ? Kb1 : Kb0;
                const int n = kg * 16 + ln15;           // key row in Kd
                f32x4 s0 = f32x4{0.f, 0.f, 0.f, 0.f};
                f32x4 s1 = f32x4{0.f, 0.f, 0.f, 0.f};
                #pragma unroll
                for (int kt = 0; kt < 8; ++kt) {
                    const int p = (kt * 4 + quad) ^ (n & 15);
                    bf16x8 kf = __builtin_bit_cast(bf16x8,
                                  *(const u32x4*)&Kd[n * 256 + p * 8]);
                    s0 = __builtin_amdgcn_mfma_f32_16x16x32_bf16(kf, qf0[kt], s0, 0, 0, 0);
                    s1 = __builtin_amdgcn_mfma_f32_16x16x32_bf16(kf, qf1[kt], s1, 0, 0, 0);
                }
                // exp (no max-sub), P-write (b64 x2), denom partials
                char* Pw = (r & 1) ? P1 : P0;
                const int q0 = qh * 32 + ln15;
                const int q1 = q0 + 16;                 // (q1&7)==(q0&7)
                const int wo = (kg * 32 + quad * 8) ^ ((q0 & 7) << 4);
                float e00 = __expf(s0[0] * SCALE), e01 = __expf(s0[1] * SCALE);
                float e02 = __expf(s0[2] * SCALE), e03 = __expf(s0[3] * SCALE);
                float e10 = __expf(s1[0] * SCALE), e11 = __expf(s1[1] * SCALE);
                float e12 = __expf(s1[2] * SCALE), e13 = __expf(s1[3] * SCALE);
                unsigned int d0 = (unsigned int)f2b(e00) | ((unsigned int)f2b(e01) << 16);
                unsigned int d1 = (unsigned int)f2b(e02) | ((unsigned int)f2b(e03) << 16);
                unsigned int d2 = (unsigned int)f2b(e10) | ((unsigned int)f2b(e11) << 16);
                unsigned int d3 = (unsigned int)f2b(e12) | ((unsigned int)f2b(e13) << 16);
                *(u32x2*)(Pw + q0 * 128 + wo) = u32x2{d0, d1};
                *(u32x2*)(Pw + q1 * 128 + wo) = u32x2{d2, d3};
                float rs0 = (e00 + e01) + (e02 + e03);
                float rs1 = (e10 + e11) + (e12 + e13);
                rs0 += __shfl_xor(rs0, 16, 64);
                rs0 += __shfl_xor(rs0, 32, 64);
                rs1 += __shfl_xor(rs1, 16, 64);
                rs1 += __shfl_xor(rs1, 32, 64);
                dacc0 += rs0;
                dacc1 += rs1;
            }
        } else {
            if (r > 0) {
                const char* Pr = ((r - 1) & 1) ? P1 : P0;
                const unsigned short* Vd = ((r - 1) & 1) ? Vb1 : Vb0;
                bf16x8 pa[2][2];
                #pragma unroll
                for (int row = 0; row < 2; ++row) {
                    const int qr = qh * 32 + row * 16 + ln15;
                    #pragma unroll
                    for (int jw = 0; jw < 2; ++jw)
                        pa[row][jw] = __builtin_bit_cast(bf16x8,
                            *(const u32x4*)(Pr + qr * 128 +
                                ((jw * 64 + quad * 16) ^ ((qr & 7) << 4))));
                }
                #pragma unroll
                for (int ct = 0; ct < 4; ++ct) {
                    const int c = ch * 64 + ct * 16 + ln15;
                    #pragma unroll
                    for (int jw = 0; jw < 2; ++jw) {
                        const int p = (jw * 4 + quad) ^ (c & 7);
                        bf16x8 vb = __builtin_bit_cast(bf16x8,
                                      *(const u32x4*)&Vd[c * 64 + p * 8]);
                        ctx[0][ct] = __builtin_amdgcn_mfma_f32_16x16x32_bf16(
                                         pa[0][jw], vb, ctx[0][ct], 0, 0, 0);
                        ctx[1][ct] = __builtin_amdgcn_mfma_f32_16x16x32_bf16(
                                         pa[1][jw], vb, ctx[1][ct], 0, 0, 0);
                    }
                }
            }
        }

        __syncthreads();   // region end: P visible, staging landed, bufs safe
    }

    // ---- denominator combine: QK waves publish, PV waves normalize ----
    if (isQK && quad == 0) {
        denomLDS[kg * 64 + qh * 32 + ln15]      = dacc0;
        denomLDS[kg * 64 + qh * 32 + 16 + ln15] = dacc1;
    }
    __syncthreads();
    if (!isQK) {
        #pragma unroll
        for (int row = 0; row < 2; ++row) {
            float rinv[4];
            #pragma unroll
            for (int rr = 0; rr < 4; ++rr) {
                const int q = qh * 32 + row * 16 + quad * 4 + rr;
                rinv[rr] = 1.0f / (denomLDS[q] + denomLDS[64 + q] +
                                   denomLDS[128 + q] + denomLDS[192 + q]);
            }
            #pragma unroll
            for (int ct = 0; ct < 4; ++ct) {
                const int c = ch * 64 + ct * 16 + ln15;
                #pragma unroll
                for (int rr = 0; rr < 4; ++rr)
                    buf[c][qh * 32 + row * 16 + quad * 4 + rr] = ctx[row][ct][rr] * rinv[rr];
            }
        }
    }
    __syncthreads();

    #pragma unroll
    for (int p = 0; p < 4; ++p) {
        const int f  = t + 1024 * p;      // 0..4095
        const int c  = f >> 4;
        const int lg = (f & 15) * 4;
        const size_t idx = ((size_t)(b * NC + c)) * NL + l0 + lg;
        float4 xv = *(const float4*)&x[idx];
        float4 cv = *(const float4*)&buf[c][lg];
        float4 o = make_float4(cv.x + xv.x, cv.y + xv.y, cv.z + xv.z, cv.w + xv.w);
        *(float4*)&out[idx] = o;
    }
}

// ---------------------------------------------------------------------------
extern "C" void kernel_launch(void* const* d_in, const int* in_sizes, int n_in,
                              void* d_out, int out_size, void* d_ws, size_t ws_size,
                              hipStream_t stream) {
    const float* x  = (const float*)d_in[0];
    const float* Wq = (const float*)d_in[1];
    const float* bq = (const float*)d_in[2];
    const float* Wk = (const float*)d_in[3];
    const float* bk = (const float*)d_in[4];
    const float* Wv = (const float*)d_in[5];
    const float* bv = (const float*)d_in[6];
    float* out = (float*)d_out;

    const size_t plane = (size_t)NB * NC * NL;       // 4.19M elems
    unsigned short* qT  = (unsigned short*)d_ws;
    unsigned short* kT  = qT + plane;
    unsigned short* v   = kT + plane;
    unsigned short* xT  = v + plane;
    unsigned short* Wbf = xT + plane;                // 3*65536 elems

    wconv_kernel<<<192, 256, 0, stream>>>(Wq, Wk, Wv, Wbf);

    dim3 gx(NL / 64, NC / 64, NB);                   // (32, 4, 8)
    xprep_kernel<<<gx, 256, 0, stream>>>(x, xT);

    qkv_mfma<<<768, 256, 0, stream>>>(xT, Wbf, bq, bk, bv, qT, kT, v);

    attn_kernel<<<256, 1024, 0, stream>>>(qT, kT, v, x, out);
}